// Round 1
// baseline (3035.744 us; speedup 1.0000x reference)
//
#include <hip/hip_runtime.h>

#define EPS 1e-5f

__global__ __launch_bounds__(256) void k_init(float* deg, float* scal, int N) {
    int i = blockIdx.x * 256 + threadIdx.x;
    if (i < N) deg[i] = 1.0f;                  // self-loop contributes 1 to degree
    if (i == 0) { scal[0] = 0.f; scal[1] = 0.f; }
}

// h[n][r] = sum_k x[n][k] * W[r][k]   (x: [N,256], W: [16,256], h: [N,16])
__global__ __launch_bounds__(256) void k_gemm(const float* __restrict__ x,
                                              const float* __restrict__ W,
                                              float* __restrict__ h, int N) {
    __shared__ float xs[16 * 260];   // 16 rows, stride 260 floats (pad kills bank conflicts)
    __shared__ float ws[16 * 260];
    const int tid = threadIdx.x;
    const int base = blockIdx.x * 16;
    for (int i = tid; i < 16 * 64; i += 256) {         // stage W as float4
        int r = i >> 6, k4 = i & 63;
        float4 v = ((const float4*)W)[i];
        *(float4*)(ws + r * 260 + k4 * 4) = v;
    }
    for (int i = tid; i < 16 * 64; i += 256) {         // stage 16 x-rows as float4
        int n = i >> 6, k4 = i & 63;
        int node = base + n;
        float4 v = make_float4(0.f, 0.f, 0.f, 0.f);
        if (node < N) v = ((const float4*)(x + (size_t)node * 256))[k4];
        *(float4*)(xs + n * 260 + k4 * 4) = v;
    }
    __syncthreads();
    const int node = tid >> 4, r = tid & 15;
    const float4* xr = (const float4*)(xs + node * 260);
    const float4* wr = (const float4*)(ws + r * 260);
    float acc = 0.f;
#pragma unroll 8
    for (int k = 0; k < 64; k++) {
        float4 a = xr[k], w = wr[k];
        acc += a.x * w.x + a.y * w.y + a.z * w.z + a.w * w.w;
    }
    int g = base + node;
    if (g < N) h[(size_t)g * 16 + r] = acc;
}

__global__ __launch_bounds__(256) void k_deg(const int* __restrict__ ei, float* __restrict__ deg, int E) {
    int e = blockIdx.x * 256 + threadIdx.x;
    if (e < E) atomicAdd(&deg[ei[E + e]], 1.0f);
}

// dinv[n] = rsqrt(deg[n]); agg[n][:] = h[n][:] * dinv[n]^2   (self-loop term, plain stores)
__global__ __launch_bounds__(256) void k_selfinit(const float* __restrict__ degv,
                                                  const float* __restrict__ h,
                                                  float* __restrict__ dinv,
                                                  float* __restrict__ agg, int N) {
    int n = blockIdx.x * 256 + threadIdx.x;
    if (n >= N) return;
    float d = rsqrtf(degv[n]);
    dinv[n] = d;
    float s = d * d;
    const float4* hr = (const float4*)(h + (size_t)n * 16);
    float4* ar = (float4*)(agg + (size_t)n * 16);
#pragma unroll
    for (int i = 0; i < 4; i++) {
        float4 v = hr[i];
        v.x *= s; v.y *= s; v.z *= s; v.w *= s;
        ar[i] = v;
    }
}

// agg[dst][:] += h[src][:] * dinv[src]*dinv[dst]   (16 fp32 atomics per edge)
__global__ __launch_bounds__(256) void k_scatter(const int* __restrict__ ei,
                                                 const float* __restrict__ h,
                                                 const float* __restrict__ dinv,
                                                 float* __restrict__ agg, int E) {
    int e = blockIdx.x * 256 + threadIdx.x;
    if (e >= E) return;
    int src = ei[e], dst = ei[E + e];
    float norm = dinv[src] * dinv[dst];
    const float4* hv = (const float4*)(h + (size_t)src * 16);
    float* out = agg + (size_t)dst * 16;
    float4 v0 = hv[0], v1 = hv[1], v2 = hv[2], v3 = hv[3];
    atomicAdd(out + 0,  v0.x * norm); atomicAdd(out + 1,  v0.y * norm);
    atomicAdd(out + 2,  v0.z * norm); atomicAdd(out + 3,  v0.w * norm);
    atomicAdd(out + 4,  v1.x * norm); atomicAdd(out + 5,  v1.y * norm);
    atomicAdd(out + 6,  v1.z * norm); atomicAdd(out + 7,  v1.w * norm);
    atomicAdd(out + 8,  v2.x * norm); atomicAdd(out + 9,  v2.y * norm);
    atomicAdd(out + 10, v2.z * norm); atomicAdd(out + 11, v2.w * norm);
    atomicAdd(out + 12, v3.x * norm); atomicAdd(out + 13, v3.y * norm);
    atomicAdd(out + 14, v3.z * norm); atomicAdd(out + 15, v3.w * norm);
}

// sum and sumsq of (agg + b) over all N*16 elements (bias folded in here and in epilogue)
__global__ __launch_bounds__(256) void k_stats(const float* __restrict__ agg,
                                               const float* __restrict__ bias,
                                               float* __restrict__ scal, int N) {
    int n = blockIdx.x * 256 + threadIdx.x;
    float s = 0.f, q = 0.f;
    if (n < N) {
        const float4* ar = (const float4*)(agg + (size_t)n * 16);
        const float4* br = (const float4*)bias;
#pragma unroll
        for (int i = 0; i < 4; i++) {
            float4 v = ar[i], bb = br[i];
            float a0 = v.x + bb.x, a1 = v.y + bb.y, a2 = v.z + bb.z, a3 = v.w + bb.w;
            s += a0 + a1 + a2 + a3;
            q += a0 * a0 + a1 * a1 + a2 * a2 + a3 * a3;
        }
    }
    for (int off = 32; off > 0; off >>= 1) {
        s += __shfl_down(s, off, 64);
        q += __shfl_down(q, off, 64);
    }
    if ((threadIdx.x & 63) == 0) { atomicAdd(&scal[0], s); atomicAdd(&scal[1], q); }
}

// per batch row: LN + PReLU on 16 channels, then x trans[16,128] -> out[B,128]
__global__ __launch_bounds__(256) void k_final(const float* __restrict__ agg,
                                               const int* __restrict__ batch,
                                               const float* __restrict__ trans,
                                               const float* __restrict__ bias,
                                               const float* __restrict__ ln_w,
                                               const float* __restrict__ ln_b,
                                               const float* __restrict__ prelu_a,
                                               const float* __restrict__ scal,
                                               float* __restrict__ out, int B, float invCnt) {
    __shared__ float tl[16 * 128];
    __shared__ float hh[2 * 16];
    const int tid = threadIdx.x;
    for (int i = tid; i < 2048; i += 256) tl[i] = trans[i];
    float mean = scal[0] * invCnt;
    float var  = scal[1] * invCnt - mean * mean;
    float inv  = rsqrtf(var + EPS);
    int row0 = blockIdx.x * 2;
    if (tid < 32) {
        int lr = tid >> 4, r = tid & 15;
        int row = row0 + lr;
        if (row < B) {
            int node = batch[row];
            float v = agg[(size_t)node * 16 + r] + bias[r];
            v = (v - mean) * inv * ln_w[r] + ln_b[r];
            float a = prelu_a[0];
            v = v >= 0.f ? v : a * v;
            hh[lr * 16 + r] = v;
        }
    }
    __syncthreads();
    int lr = tid >> 7, d = tid & 127;
    int row = row0 + lr;
    if (row >= B) return;
    const float* hrow = hh + lr * 16;
    float acc = 0.f;
#pragma unroll
    for (int r = 0; r < 16; r++) acc += hrow[r] * tl[r * 128 + d];
    out[(size_t)row * 128 + d] = acc;
}

extern "C" void kernel_launch(void* const* d_in, const int* in_sizes, int n_in,
                              void* d_out, int out_size, void* d_ws, size_t ws_size,
                              hipStream_t stream) {
    const float* x       = (const float*)d_in[0];
    const int*   ei      = (const int*)d_in[1];
    const float* trans   = (const float*)d_in[2];
    const int*   batch   = (const int*)d_in[3];
    const float* W       = (const float*)d_in[4];
    const float* bias    = (const float*)d_in[5];
    const float* ln_w    = (const float*)d_in[6];
    const float* ln_b    = (const float*)d_in[7];
    const float* prelu_a = (const float*)d_in[8];
    float* out = (float*)d_out;

    const int N = in_sizes[0] / 256;   // 100000
    const int E = in_sizes[1] / 2;     // 3200000
    const int B = in_sizes[3];         // 16384

    float* ws   = (float*)d_ws;
    float* h    = ws;                        // N*16
    float* agg  = h   + (size_t)N * 16;      // N*16
    float* deg  = agg + (size_t)N * 16;      // N
    float* dinv = deg + N;                   // N
    float* scal = dinv + N;                  // 2

    int nb = (N + 255) / 256;
    int eb = (E + 255) / 256;

    hipLaunchKernelGGL(k_init,     dim3(nb),            dim3(256), 0, stream, deg, scal, N);
    hipLaunchKernelGGL(k_gemm,     dim3((N + 15) / 16), dim3(256), 0, stream, x, W, h, N);
    hipLaunchKernelGGL(k_deg,      dim3(eb),            dim3(256), 0, stream, ei, deg, E);
    hipLaunchKernelGGL(k_selfinit, dim3(nb),            dim3(256), 0, stream, deg, h, dinv, agg, N);
    hipLaunchKernelGGL(k_scatter,  dim3(eb),            dim3(256), 0, stream, ei, h, dinv, agg, E);
    hipLaunchKernelGGL(k_stats,    dim3(nb),            dim3(256), 0, stream, agg, bias, scal, N);
    hipLaunchKernelGGL(k_final,    dim3((B + 1) / 2),   dim3(256), 0, stream, agg, batch, trans, bias,
                       ln_w, ln_b, prelu_a, scal, out, B, 1.0f / (float)(N * 16));
}

// Round 2
// 809.707 us; speedup vs baseline: 3.7492x; 3.7492x over previous
//
#include <hip/hip_runtime.h>

#define EPS 1e-5f

__global__ __launch_bounds__(256) void k_zero(unsigned* cnt, float* scal, int N) {
    int i = blockIdx.x * 256 + threadIdx.x;
    if (i < N) cnt[i] = 0u;
    if (i == 0) { scal[0] = 0.f; scal[1] = 0.f; }
}

__global__ __launch_bounds__(256) void k_hist(const int* __restrict__ ei, unsigned* __restrict__ cnt, int E) {
    int e = blockIdx.x * 256 + threadIdx.x;
    if (e < E) atomicAdd(&cnt[ei[E + e]], 1u);
}

// h[n][r] = sum_k x[n][k] * W[r][k]   (x: [N,256], W: [16,256], h: [N,16])
__global__ __launch_bounds__(256) void k_gemm(const float* __restrict__ x,
                                              const float* __restrict__ W,
                                              float* __restrict__ h, int N) {
    __shared__ float xs[16 * 260];
    __shared__ float ws[16 * 260];
    const int tid = threadIdx.x;
    const int base = blockIdx.x * 16;
    for (int i = tid; i < 16 * 64; i += 256) {
        int r = i >> 6, k4 = i & 63;
        float4 v = ((const float4*)W)[i];
        *(float4*)(ws + r * 260 + k4 * 4) = v;
    }
    for (int i = tid; i < 16 * 64; i += 256) {
        int n = i >> 6, k4 = i & 63;
        int node = base + n;
        float4 v = make_float4(0.f, 0.f, 0.f, 0.f);
        if (node < N) v = ((const float4*)(x + (size_t)node * 256))[k4];
        *(float4*)(xs + n * 260 + k4 * 4) = v;
    }
    __syncthreads();
    const int node = tid >> 4, r = tid & 15;
    const float4* xr = (const float4*)(xs + node * 260);
    const float4* wr = (const float4*)(ws + r * 260);
    float acc = 0.f;
#pragma unroll 8
    for (int k = 0; k < 64; k++) {
        float4 a = xr[k], w = wr[k];
        acc += a.x * w.x + a.y * w.y + a.z * w.z + a.w * w.w;
    }
    int g = base + node;
    if (g < N) h[(size_t)g * 16 + r] = acc;
}

// P1: per-1024-chunk sums of cnt
__global__ __launch_bounds__(256) void k_scan1(const unsigned* __restrict__ cnt,
                                               unsigned* __restrict__ bsum, int N) {
    int b = blockIdx.x, t = threadIdx.x;
    int i0 = b * 1024 + t * 4;
    unsigned s = 0;
    for (int k = 0; k < 4; k++) { int i = i0 + k; if (i < N) s += cnt[i]; }
    for (int off = 32; off > 0; off >>= 1) s += __shfl_down(s, off, 64);
    __shared__ unsigned wsh[4];
    if ((t & 63) == 0) wsh[t >> 6] = s;
    __syncthreads();
    if (t == 0) bsum[b] = wsh[0] + wsh[1] + wsh[2] + wsh[3];
}

// P2: exclusive scan of bsum[nb] (nb <= 128); also start[N] = E
__global__ __launch_bounds__(128) void k_scan2(const unsigned* __restrict__ bsum,
                                               unsigned* __restrict__ boff,
                                               unsigned* __restrict__ start,
                                               int nb, int N, int E) {
    __shared__ unsigned sh[128];
    int t = threadIdx.x;
    unsigned v = (t < nb) ? bsum[t] : 0u;
    sh[t] = v;
    __syncthreads();
    for (int off = 1; off < 128; off <<= 1) {
        unsigned add = (t >= off) ? sh[t - off] : 0u;
        __syncthreads();
        sh[t] += add;
        __syncthreads();
    }
    if (t < nb) boff[t] = sh[t] - v;          // exclusive
    if (t == 0) start[N] = (unsigned)E;
}

// P3: write start/cursor (exclusive prefix) and dinv = rsqrt(cnt+1)
__global__ __launch_bounds__(256) void k_scan3(const unsigned* __restrict__ cnt,
                                               const unsigned* __restrict__ boff,
                                               unsigned* __restrict__ start,
                                               unsigned* __restrict__ cursor,
                                               float* __restrict__ dinv, int N) {
    int b = blockIdx.x, t = threadIdx.x;
    int lane = t & 63, wid = t >> 6;
    int i0 = b * 1024 + t * 4;
    unsigned v[4]; unsigned ls = 0;
    for (int k = 0; k < 4; k++) { int i = i0 + k; v[k] = (i < N) ? cnt[i] : 0u; ls += v[k]; }
    unsigned inc = ls;
    for (int off = 1; off < 64; off <<= 1) {
        unsigned u = __shfl_up(inc, off, 64);
        if (lane >= off) inc += u;
    }
    unsigned lex = inc - ls;
    __shared__ unsigned wsum[4];
    if (lane == 63) wsum[wid] = inc;
    __syncthreads();
    unsigned wbase = 0;
    for (int w = 0; w < wid; w++) wbase += wsum[w];
    unsigned base = boff[b] + wbase + lex;
    for (int k = 0; k < 4; k++) {
        int i = i0 + k;
        if (i < N) {
            start[i] = base; cursor[i] = base;
            dinv[i] = rsqrtf((float)(v[k] + 1u));   // +1 = self-loop
            base += v[k];
        }
    }
}

// position scatter: sorted[atomicAdd(cursor[dst])] = src
__global__ __launch_bounds__(256) void k_pos(const int* __restrict__ ei,
                                             unsigned* __restrict__ cursor,
                                             unsigned* __restrict__ sorted, int E) {
    int e = blockIdx.x * 256 + threadIdx.x;
    if (e >= E) return;
    int src = ei[e], dst = ei[E + e];
    unsigned p = atomicAdd(&cursor[dst], 1u);
    sorted[p] = (unsigned)src;
}

// atomic-free pull aggregation: 16 lanes per dst, channel r per lane.
// agg[d][r] = (sum_{src in N(d)} h[src][r]*dinv[src]) * dinv[d] + h[d][r]*dinv[d]^2
// Fused LN-stats partial sums (with bias) -> 2 atomics per block.
__global__ __launch_bounds__(256) void k_agg(const unsigned* __restrict__ start,
                                             const unsigned* __restrict__ sorted,
                                             const float* __restrict__ h,
                                             const float* __restrict__ dinv,
                                             const float* __restrict__ bias,
                                             float* __restrict__ agg,
                                             float* __restrict__ scal, int N) {
    int t = threadIdx.x;
    int g = t >> 4, r = t & 15;
    int d = blockIdx.x * 16 + g;
    float sv = 0.f;
    if (d < N) {
        unsigned s0 = start[d], s1 = start[d + 1];
        float acc = 0.f;
        for (unsigned j = s0; j < s1; j++) {
            int src = (int)sorted[j];
            acc += h[(size_t)src * 16 + r] * dinv[src];
        }
        float dd = dinv[d];
        acc = acc * dd + h[(size_t)d * 16 + r] * dd * dd;
        agg[(size_t)d * 16 + r] = acc;
        sv = acc + bias[r];
    }
    float s = sv, q = sv * sv;
    for (int off = 32; off > 0; off >>= 1) {
        s += __shfl_down(s, off, 64);
        q += __shfl_down(q, off, 64);
    }
    __shared__ float ss[4], qq[4];
    int lane = t & 63, wid = t >> 6;
    if (lane == 0) { ss[wid] = s; qq[wid] = q; }
    __syncthreads();
    if (t == 0) {
        atomicAdd(&scal[0], ss[0] + ss[1] + ss[2] + ss[3]);
        atomicAdd(&scal[1], qq[0] + qq[1] + qq[2] + qq[3]);
    }
}

// per batch row: LN + PReLU on 16 channels, then x trans[16,128] -> out[B,128]
__global__ __launch_bounds__(256) void k_final(const float* __restrict__ agg,
                                               const int* __restrict__ batch,
                                               const float* __restrict__ trans,
                                               const float* __restrict__ bias,
                                               const float* __restrict__ ln_w,
                                               const float* __restrict__ ln_b,
                                               const float* __restrict__ prelu_a,
                                               const float* __restrict__ scal,
                                               float* __restrict__ out, int B, float invCnt) {
    __shared__ float tl[16 * 128];
    __shared__ float hh[2 * 16];
    const int tid = threadIdx.x;
    for (int i = tid; i < 2048; i += 256) tl[i] = trans[i];
    float mean = scal[0] * invCnt;
    float var  = scal[1] * invCnt - mean * mean;
    float inv  = rsqrtf(var + EPS);
    int row0 = blockIdx.x * 2;
    if (tid < 32) {
        int lr = tid >> 4, r = tid & 15;
        int row = row0 + lr;
        if (row < B) {
            int node = batch[row];
            float v = agg[(size_t)node * 16 + r] + bias[r];
            v = (v - mean) * inv * ln_w[r] + ln_b[r];
            float a = prelu_a[0];
            v = v >= 0.f ? v : a * v;
            hh[lr * 16 + r] = v;
        }
    }
    __syncthreads();
    int lr = tid >> 7, d = tid & 127;
    int row = row0 + lr;
    if (row >= B) return;
    const float* hrow = hh + lr * 16;
    float acc = 0.f;
#pragma unroll
    for (int r = 0; r < 16; r++) acc += hrow[r] * tl[r * 128 + d];
    out[(size_t)row * 128 + d] = acc;
}

extern "C" void kernel_launch(void* const* d_in, const int* in_sizes, int n_in,
                              void* d_out, int out_size, void* d_ws, size_t ws_size,
                              hipStream_t stream) {
    const float* x       = (const float*)d_in[0];
    const int*   ei      = (const int*)d_in[1];
    const float* trans   = (const float*)d_in[2];
    const int*   batch   = (const int*)d_in[3];
    const float* W       = (const float*)d_in[4];
    const float* bias    = (const float*)d_in[5];
    const float* ln_w    = (const float*)d_in[6];
    const float* ln_b    = (const float*)d_in[7];
    const float* prelu_a = (const float*)d_in[8];
    float* out = (float*)d_out;

    const int N = in_sizes[0] / 256;   // 100000
    const int E = in_sizes[1] / 2;     // 3200000
    const int B = in_sizes[3];         // 16384

    char* p = (char*)d_ws;
    float*    h      = (float*)p;      p += (size_t)N * 16 * 4;
    float*    agg    = (float*)p;      p += (size_t)N * 16 * 4;
    unsigned* cnt    = (unsigned*)p;   p += (size_t)N * 4;
    unsigned* start  = (unsigned*)p;   p += (size_t)(N + 1) * 4;
    unsigned* cursor = (unsigned*)p;   p += (size_t)N * 4;
    float*    dinv   = (float*)p;      p += (size_t)N * 4;
    unsigned* bsum   = (unsigned*)p;   p += 128 * 4;
    unsigned* boff   = (unsigned*)p;   p += 128 * 4;
    float*    scal   = (float*)p;      p += 2 * 4;
    unsigned* sorted = (unsigned*)p;   p += (size_t)E * 4;

    int nb  = (N + 255) / 256;
    int eb  = (E + 255) / 256;
    int nb1 = (N + 1023) / 1024;       // 98 <= 128

    hipLaunchKernelGGL(k_zero,  dim3(nb),            dim3(256), 0, stream, cnt, scal, N);
    hipLaunchKernelGGL(k_hist,  dim3(eb),            dim3(256), 0, stream, ei, cnt, E);
    hipLaunchKernelGGL(k_gemm,  dim3((N + 15) / 16), dim3(256), 0, stream, x, W, h, N);
    hipLaunchKernelGGL(k_scan1, dim3(nb1),           dim3(256), 0, stream, cnt, bsum, N);
    hipLaunchKernelGGL(k_scan2, dim3(1),             dim3(128), 0, stream, bsum, boff, start, nb1, N, E);
    hipLaunchKernelGGL(k_scan3, dim3(nb1),           dim3(256), 0, stream, cnt, boff, start, cursor, dinv, N);
    hipLaunchKernelGGL(k_pos,   dim3(eb),            dim3(256), 0, stream, ei, cursor, sorted, E);
    hipLaunchKernelGGL(k_agg,   dim3((N + 15) / 16), dim3(256), 0, stream, start, sorted, h, dinv, bias, agg, scal, N);
    hipLaunchKernelGGL(k_final, dim3((B + 1) / 2),   dim3(256), 0, stream, agg, batch, trans, bias,
                       ln_w, ln_b, prelu_a, scal, out, B, 1.0f / (float)(N * 16));
}

// Round 3
// 624.198 us; speedup vs baseline: 4.8634x; 1.2972x over previous
//
#include <hip/hip_runtime.h>

#define EPS 1e-5f
#define BSHIFT 9
#define BSIZE  512
#define NBMAX  256   // covers N up to 131072

__global__ __launch_bounds__(256) void k_zero(unsigned* ghist, float* scal, int NB) {
    int t = threadIdx.x;
    if (t < NB) ghist[t] = 0u;
    if (t == 0) { scal[0] = 0.f; scal[1] = 0.f; }
}

// h[n][r] = sum_k x[n][k] * W[r][k]   (x: [N,256], W: [16,256], h: [N,16])
__global__ __launch_bounds__(256) void k_gemm(const float* __restrict__ x,
                                              const float* __restrict__ W,
                                              float* __restrict__ h, int N) {
    __shared__ float xs[16 * 260];
    __shared__ float ws[16 * 260];
    const int tid = threadIdx.x;
    const int base = blockIdx.x * 16;
    for (int i = tid; i < 16 * 64; i += 256) {
        int r = i >> 6, k4 = i & 63;
        float4 v = ((const float4*)W)[i];
        *(float4*)(ws + r * 260 + k4 * 4) = v;
    }
    for (int i = tid; i < 16 * 64; i += 256) {
        int n = i >> 6, k4 = i & 63;
        int node = base + n;
        float4 v = make_float4(0.f, 0.f, 0.f, 0.f);
        if (node < N) v = ((const float4*)(x + (size_t)node * 256))[k4];
        *(float4*)(xs + n * 260 + k4 * 4) = v;
    }
    __syncthreads();
    const int node = tid >> 4, r = tid & 15;
    const float4* xr = (const float4*)(xs + node * 260);
    const float4* wr = (const float4*)(ws + r * 260);
    float acc = 0.f;
#pragma unroll 8
    for (int k = 0; k < 64; k++) {
        float4 a = xr[k], w = wr[k];
        acc += a.x * w.x + a.y * w.y + a.z * w.z + a.w * w.w;
    }
    int g = base + node;
    if (g < N) h[(size_t)g * 16 + r] = acc;
}

// bucket histogram: LDS-aggregated, ~NB global atomics per block
__global__ __launch_bounds__(256) void k_bhist(const int* __restrict__ ei,
                                               unsigned* __restrict__ ghist, int E, int NB) {
    __shared__ unsigned sh[NBMAX];
    int t = threadIdx.x;
    for (int i = t; i < NB; i += 256) sh[i] = 0u;
    __syncthreads();
    const int4* dst4 = (const int4*)(ei + E);
    int E4 = E >> 2;
    int base4 = blockIdx.x * 2048;
#pragma unroll
    for (int i = 0; i < 8; i++) {
        int idx = base4 + i * 256 + t;
        if (idx < E4) {
            int4 d = dst4[idx];
            atomicAdd(&sh[d.x >> BSHIFT], 1u);
            atomicAdd(&sh[d.y >> BSHIFT], 1u);
            atomicAdd(&sh[d.z >> BSHIFT], 1u);
            atomicAdd(&sh[d.w >> BSHIFT], 1u);
        }
    }
    __syncthreads();
    for (int i = t; i < NB; i += 256) if (sh[i]) atomicAdd(&ghist[i], sh[i]);
}

// exclusive scan of ghist[NB] -> base, cursor; base[NB] = E
__global__ __launch_bounds__(256) void k_bscan(const unsigned* __restrict__ ghist,
                                               unsigned* __restrict__ base,
                                               unsigned* __restrict__ cursor, int NB, int E) {
    __shared__ unsigned sh[256];
    int t = threadIdx.x;
    unsigned v = (t < NB) ? ghist[t] : 0u;
    sh[t] = v;
    __syncthreads();
    for (int off = 1; off < 256; off <<= 1) {
        unsigned a = (t >= off) ? sh[t - off] : 0u;
        __syncthreads();
        sh[t] += a;
        __syncthreads();
    }
    if (t < NB) { unsigned ex = sh[t] - v; base[t] = ex; cursor[t] = ex; }
    if (t == 0) base[NB] = (unsigned)E;
}

// partition edges into bucket streams; packed u32 = src | (dst&511)<<17
__global__ __launch_bounds__(256) void k_bpart(const int* __restrict__ ei,
                                               unsigned* __restrict__ cursor,
                                               unsigned* __restrict__ sorted, int E, int NB) {
    __shared__ unsigned cnt[NBMAX];
    __shared__ unsigned lbase[NBMAX];
    int t = threadIdx.x;
    for (int i = t; i < NB; i += 256) cnt[i] = 0u;
    __syncthreads();
    const int4* src4 = (const int4*)ei;
    const int4* dst4 = (const int4*)(ei + E);
    int E4 = E >> 2;
    int base4 = blockIdx.x * 2048;
    // phase 1: block-local counts
#pragma unroll
    for (int i = 0; i < 8; i++) {
        int idx = base4 + i * 256 + t;
        if (idx < E4) {
            int4 d = dst4[idx];
            atomicAdd(&cnt[d.x >> BSHIFT], 1u);
            atomicAdd(&cnt[d.y >> BSHIFT], 1u);
            atomicAdd(&cnt[d.z >> BSHIFT], 1u);
            atomicAdd(&cnt[d.w >> BSHIFT], 1u);
        }
    }
    __syncthreads();
    // reserve global space (<= NB atomics per block), reset cnt as running offset
    for (int i = t; i < NB; i += 256) {
        unsigned c = cnt[i];
        lbase[i] = c ? atomicAdd(&cursor[i], c) : 0u;
        cnt[i] = 0u;
    }
    __syncthreads();
    // phase 2: place edges
#pragma unroll
    for (int i = 0; i < 8; i++) {
        int idx = base4 + i * 256 + t;
        if (idx < E4) {
            int4 s = src4[idx];
            int4 d = dst4[idx];
            {
                int b = d.x >> BSHIFT; unsigned off = atomicAdd(&cnt[b], 1u);
                sorted[lbase[b] + off] = (unsigned)s.x | ((unsigned)(d.x & (BSIZE - 1)) << 17);
            }
            {
                int b = d.y >> BSHIFT; unsigned off = atomicAdd(&cnt[b], 1u);
                sorted[lbase[b] + off] = (unsigned)s.y | ((unsigned)(d.y & (BSIZE - 1)) << 17);
            }
            {
                int b = d.z >> BSHIFT; unsigned off = atomicAdd(&cnt[b], 1u);
                sorted[lbase[b] + off] = (unsigned)s.z | ((unsigned)(d.z & (BSIZE - 1)) << 17);
            }
            {
                int b = d.w >> BSHIFT; unsigned off = atomicAdd(&cnt[b], 1u);
                sorted[lbase[b] + off] = (unsigned)s.w | ((unsigned)(d.w & (BSIZE - 1)) << 17);
            }
        }
    }
}

// per-bucket degree -> dinv = rsqrt(deg+1)
__global__ __launch_bounds__(256) void k_bdeg(const unsigned* __restrict__ base,
                                              const unsigned* __restrict__ sorted,
                                              float* __restrict__ dinv, int N) {
    __shared__ unsigned deg[BSIZE];
    int b = blockIdx.x, t = threadIdx.x;
    deg[t] = 0u; deg[t + 256] = 0u;
    __syncthreads();
    unsigned s0 = base[b], s1 = base[b + 1];
    for (unsigned j = s0 + t; j < s1; j += 256)
        atomicAdd(&deg[sorted[j] >> 17], 1u);
    __syncthreads();
    int n0 = b << BSHIFT;
    if (n0 + t < N)       dinv[n0 + t]       = rsqrtf((float)(deg[t] + 1u));
    if (n0 + 256 + t < N) dinv[n0 + 256 + t] = rsqrtf((float)(deg[t + 256] + 1u));
}

// per-bucket LDS-tile aggregation; fused self-loop + LN stats
__global__ __launch_bounds__(512) void k_bagg(const unsigned* __restrict__ base,
                                              const unsigned* __restrict__ sorted,
                                              const float* __restrict__ h,
                                              const float* __restrict__ dinv,
                                              const float* __restrict__ bias,
                                              float* __restrict__ agg,
                                              float* __restrict__ scal, int N) {
    __shared__ float tile[BSIZE * 17];   // stride 17 breaks bank-conflict patterns
    int t = threadIdx.x;
    for (int i = t; i < BSIZE * 17; i += 512) tile[i] = 0.f;
    __syncthreads();
    int b = blockIdx.x;
    unsigned s0 = base[b], s1 = base[b + 1];
    int G = t >> 4, ch = t & 15;          // 32 groups of 16 lanes; one edge per group
    int nbase = b << BSHIFT;
    for (unsigned j = s0 + G; j < s1; j += 32) {
        unsigned u = sorted[j];           // broadcast within the 16-lane group
        int src = (int)(u & 0x1FFFFu);
        int dlo = (int)(u >> 17);
        float c = dinv[src] * dinv[nbase + dlo];
        float v = h[(size_t)src * 16 + ch];
        atomicAdd(&tile[dlo * 17 + ch], v * c);
    }
    __syncthreads();
    float s = 0.f, q = 0.f;
    int node = nbase + t;
    if (node < N) {
        float dd = dinv[node];
        float sc = dd * dd;
        const float* hn = h + (size_t)node * 16;
        float* an = agg + (size_t)node * 16;
#pragma unroll
        for (int c4 = 0; c4 < 4; c4++) {
            float4 hv = ((const float4*)hn)[c4];
            float4 bv = ((const float4*)bias)[c4];
            float4 o;
            o.x = tile[t * 17 + c4 * 4 + 0] + hv.x * sc;
            o.y = tile[t * 17 + c4 * 4 + 1] + hv.y * sc;
            o.z = tile[t * 17 + c4 * 4 + 2] + hv.z * sc;
            o.w = tile[t * 17 + c4 * 4 + 3] + hv.w * sc;
            ((float4*)an)[c4] = o;
            float a0 = o.x + bv.x, a1 = o.y + bv.y, a2 = o.z + bv.z, a3 = o.w + bv.w;
            s += a0 + a1 + a2 + a3;
            q += a0 * a0 + a1 * a1 + a2 * a2 + a3 * a3;
        }
    }
    for (int off = 32; off > 0; off >>= 1) {
        s += __shfl_down(s, off, 64);
        q += __shfl_down(q, off, 64);
    }
    __shared__ float ss[8], qq[8];
    int lane = t & 63, wid = t >> 6;
    if (lane == 0) { ss[wid] = s; qq[wid] = q; }
    __syncthreads();
    if (t == 0) {
        float S = 0.f, Q = 0.f;
        for (int w = 0; w < 8; w++) { S += ss[w]; Q += qq[w]; }
        atomicAdd(&scal[0], S);
        atomicAdd(&scal[1], Q);
    }
}

// per batch row: LN + PReLU on 16 channels, then x trans[16,128] -> out[B,128]
__global__ __launch_bounds__(256) void k_final(const float* __restrict__ agg,
                                               const int* __restrict__ batch,
                                               const float* __restrict__ trans,
                                               const float* __restrict__ bias,
                                               const float* __restrict__ ln_w,
                                               const float* __restrict__ ln_b,
                                               const float* __restrict__ prelu_a,
                                               const float* __restrict__ scal,
                                               float* __restrict__ out, int B, float invCnt) {
    __shared__ float tl[16 * 128];
    __shared__ float hh[2 * 16];
    const int tid = threadIdx.x;
    for (int i = tid; i < 2048; i += 256) tl[i] = trans[i];
    float mean = scal[0] * invCnt;
    float var  = scal[1] * invCnt - mean * mean;
    float inv  = rsqrtf(var + EPS);
    int row0 = blockIdx.x * 2;
    if (tid < 32) {
        int lr = tid >> 4, r = tid & 15;
        int row = row0 + lr;
        if (row < B) {
            int node = batch[row];
            float v = agg[(size_t)node * 16 + r] + bias[r];
            v = (v - mean) * inv * ln_w[r] + ln_b[r];
            float a = prelu_a[0];
            v = v >= 0.f ? v : a * v;
            hh[lr * 16 + r] = v;
        }
    }
    __syncthreads();
    int lr = tid >> 7, d = tid & 127;
    int row = row0 + lr;
    if (row >= B) return;
    const float* hrow = hh + lr * 16;
    float acc = 0.f;
#pragma unroll
    for (int r = 0; r < 16; r++) acc += hrow[r] * tl[r * 128 + d];
    out[(size_t)row * 128 + d] = acc;
}

extern "C" void kernel_launch(void* const* d_in, const int* in_sizes, int n_in,
                              void* d_out, int out_size, void* d_ws, size_t ws_size,
                              hipStream_t stream) {
    const float* x       = (const float*)d_in[0];
    const int*   ei      = (const int*)d_in[1];
    const float* trans   = (const float*)d_in[2];
    const int*   batch   = (const int*)d_in[3];
    const float* W       = (const float*)d_in[4];
    const float* bias    = (const float*)d_in[5];
    const float* ln_w    = (const float*)d_in[6];
    const float* ln_b    = (const float*)d_in[7];
    const float* prelu_a = (const float*)d_in[8];
    float* out = (float*)d_out;

    const int N = in_sizes[0] / 256;   // 100000
    const int E = in_sizes[1] / 2;     // 3200000
    const int B = in_sizes[3];         // 16384
    const int NB = (N + BSIZE - 1) >> BSHIFT;   // 196

    char* p = (char*)d_ws;
    float*    h      = (float*)p;      p += (size_t)N * 16 * 4;
    float*    agg    = (float*)p;      p += (size_t)N * 16 * 4;
    unsigned* sorted = (unsigned*)p;   p += (size_t)E * 4;
    float*    dinv   = (float*)p;      p += (size_t)N * 4;
    unsigned* ghist  = (unsigned*)p;   p += NBMAX * 4;
    unsigned* base   = (unsigned*)p;   p += (NBMAX + 1) * 4;
    unsigned* cursor = (unsigned*)p;   p += NBMAX * 4;
    float*    scal   = (float*)p;      p += 2 * 4;

    int E4 = E >> 2;
    int pb = (E4 + 2047) / 2048;       // blocks for hist/part (8192 edges each)

    hipLaunchKernelGGL(k_zero,  dim3(1),             dim3(256), 0, stream, ghist, scal, NB);
    hipLaunchKernelGGL(k_gemm,  dim3((N + 15) / 16), dim3(256), 0, stream, x, W, h, N);
    hipLaunchKernelGGL(k_bhist, dim3(pb),            dim3(256), 0, stream, ei, ghist, E, NB);
    hipLaunchKernelGGL(k_bscan, dim3(1),             dim3(256), 0, stream, ghist, base, cursor, NB, E);
    hipLaunchKernelGGL(k_bpart, dim3(pb),            dim3(256), 0, stream, ei, cursor, sorted, E, NB);
    hipLaunchKernelGGL(k_bdeg,  dim3(NB),            dim3(256), 0, stream, base, sorted, dinv, N);
    hipLaunchKernelGGL(k_bagg,  dim3(NB),            dim3(512), 0, stream, base, sorted, h, dinv, bias, agg, scal, N);
    hipLaunchKernelGGL(k_final, dim3((B + 1) / 2),   dim3(256), 0, stream, agg, batch, trans, bias,
                       ln_w, ln_b, prelu_a, scal, out, B, 1.0f / (float)(N * 16));
}